// Round 1
// baseline (250.171 us; speedup 1.0000x reference)
//
#include <hip/hip_runtime.h>
#include <cstdint>
#include <cstddef>

#define IN_C  512
#define OUT_C 1024
#define NSAMP 8192

#define BM 64
#define BN 64
#define BK 64

typedef __bf16 bf16x8 __attribute__((ext_vector_type(8)));
typedef float  f32x4  __attribute__((ext_vector_type(4)));

__device__ __forceinline__ unsigned short f2bf(float f) {
    unsigned int u = __float_as_uint(f);
    u += 0x7FFFu + ((u >> 16) & 1u);   // round-to-nearest-even
    return (unsigned short)(u >> 16);
}

__device__ __forceinline__ float sigmoid_f(float x) {
    return 1.0f / (1.0f + __expf(-x));
}
__device__ __forceinline__ float tanh_f(float x) {
    float e = __expf(2.0f * x);
    return 1.0f - 2.0f / (e + 1.0f);
}

// ---- transpose + f32->bf16: in (R x C) row-major -> out (C x R) row-major ----
__global__ void tcvt_kernel(const float* __restrict__ in, unsigned short* __restrict__ out,
                            int R, int C) {
    __shared__ float t[32][33];
    const int tx = threadIdx.x;   // 0..31
    const int ty = threadIdx.y;   // 0..7
    const int c0 = blockIdx.x * 32;
    const int r0 = blockIdx.y * 32;
#pragma unroll
    for (int i = 0; i < 4; ++i)
        t[ty + i * 8][tx] = in[(size_t)(r0 + ty + i * 8) * C + (c0 + tx)];
    __syncthreads();
#pragma unroll
    for (int i = 0; i < 4; ++i)
        out[(size_t)(c0 + ty + i * 8) * R + (r0 + tx)] = f2bf(t[tx][ty + i * 8]);
}

// ---- straight f32->bf16 convert, 4 elems/thread ----
__global__ void cvt_kernel(const float* __restrict__ in, unsigned short* __restrict__ out, int n4) {
    int idx = blockIdx.x * blockDim.x + threadIdx.x;
    if (idx < n4) {
        float4 v = reinterpret_cast<const float4*>(in)[idx];
        ushort4 o;
        o.x = f2bf(v.x); o.y = f2bf(v.y); o.z = f2bf(v.z); o.w = f2bf(v.w);
        reinterpret_cast<ushort4*>(out)[idx] = o;
    }
}

// ---- fused MDLSTM: 64x64 tile, 4 waves, 8 accumulator tiles (4 gates x 2 dirs) ----
__global__ __launch_bounds__(256, 2) void mdlstm_main(
    const unsigned short* __restrict__ xT,    // [NSAMP][IN_C]  bf16
    const unsigned short* __restrict__ h0T,   // [NSAMP][OUT_C] bf16
    const unsigned short* __restrict__ h1T,   // [NSAMP][OUT_C] bf16
    const unsigned short* __restrict__ wx,    // [4][OUT_C][IN_C]  bf16 (i,f,g,o)
    const unsigned short* __restrict__ wh,    // [4][OUT_C][OUT_C] bf16
    const float* __restrict__ b_i, const float* __restrict__ b_f,
    const float* __restrict__ b_g, const float* __restrict__ b_o,
    const float* __restrict__ cp0, const float* __restrict__ cp1,
    const float* __restrict__ wsum,
    float* __restrict__ out)
{
    // LDS: 4 A-tiles (gates) + 2 B-tiles = 6 x 8KB = 48KB, single-buffered
    __shared__ __align__(16) unsigned char smem[6 * 8192];

    const int tid  = threadIdx.x;
    const int lane = tid & 63;
    const int wid  = tid >> 6;
    const int wm   = wid >> 1;      // 0..1 : wave row
    const int wn   = wid & 1;       // 0..1 : wave col
    const int g4   = lane >> 4;     // 0..3
    const int l16  = lane & 15;

    const int brow = blockIdx.y * BM;
    const int bcol = blockIdx.x * BN;

    f32x4 acc[2][4][2][2];
#pragma unroll
    for (int d = 0; d < 2; ++d)
#pragma unroll
        for (int q = 0; q < 4; ++q)
#pragma unroll
            for (int a = 0; a < 2; ++a)
#pragma unroll
                for (int b = 0; b < 2; ++b)
                    acc[d][q][a][b] = (f32x4){0.f, 0.f, 0.f, 0.f};

    // Stage one 64x64 bf16 tile (8KB) into LDS. LDS dest is linear (DMA requirement);
    // the XOR swizzle is applied to the GLOBAL source address (rule #21), and the
    // same XOR is applied on the ds_read side -> conflict-free reads.
    auto stage_tile = [&](const unsigned short* gbase, int pitch_bytes, int k0bytes, int lds_base) {
#pragma unroll
        for (int j = 0; j < 2; ++j) {
            const int slot = wid * 2 + j;              // 0..7 across 4 waves
            const int u    = slot * 1024 + lane * 16;  // linear LDS offset in tile
            const int row  = u >> 7;                   // 128B per row (BK=64 bf16)
            const int kb   = u & 127;
            const char* src = (const char*)gbase + (size_t)row * pitch_bytes + k0bytes
                              + (kb ^ ((row & 7) << 4));
            __builtin_amdgcn_global_load_lds((const unsigned int*)src,
                                             (unsigned int*)(smem + lds_base + slot * 1024),
                                             16, 0, 0);
        }
    };

    auto frag_at = [&](int lds_base, int row, int kbyte) -> bf16x8 {
        const int off = lds_base + row * 128 + (kbyte ^ ((row & 7) << 4));
        return *reinterpret_cast<const bf16x8*>(smem + off);
    };

    // ---------------- phase X: K = 512, B = xT, A = wx, accumulate into acc[0] ----------------
    for (int st = 0; st < IN_C / BK; ++st) {
        const int k0b = st * BK * 2;
#pragma unroll
        for (int q = 0; q < 4; ++q)
            stage_tile(wx + (size_t)q * OUT_C * IN_C + (size_t)brow * IN_C, IN_C * 2, k0b, q * 8192);
        stage_tile(xT + (size_t)bcol * IN_C, IN_C * 2, k0b, 4 * 8192);
        __syncthreads();
#pragma unroll
        for (int kk = 0; kk < 2; ++kk) {
            const int kbyte = kk * 64 + g4 * 16;
            bf16x8 afr[4][2], bfr[2];
#pragma unroll
            for (int q = 0; q < 4; ++q)
#pragma unroll
                for (int fm = 0; fm < 2; ++fm)
                    afr[q][fm] = frag_at(q * 8192, wm * 32 + fm * 16 + l16, kbyte);
#pragma unroll
            for (int fn = 0; fn < 2; ++fn)
                bfr[fn] = frag_at(4 * 8192, wn * 32 + fn * 16 + l16, kbyte);
#pragma unroll
            for (int q = 0; q < 4; ++q)
#pragma unroll
                for (int fm = 0; fm < 2; ++fm)
#pragma unroll
                    for (int fn = 0; fn < 2; ++fn)
                        acc[0][q][fm][fn] = __builtin_amdgcn_mfma_f32_16x16x32_bf16(
                            afr[q][fm], bfr[fn], acc[0][q][fm][fn], 0, 0, 0);
        }
        __syncthreads();
    }

    // x-projection is shared by both directions
#pragma unroll
    for (int q = 0; q < 4; ++q)
#pragma unroll
        for (int a = 0; a < 2; ++a)
#pragma unroll
            for (int b = 0; b < 2; ++b)
                acc[1][q][a][b] = acc[0][q][a][b];

    // ---------------- phase H: K = 1024, B = {h0T,h1T}, A = wh (shared) ----------------
    for (int st = 0; st < OUT_C / BK; ++st) {
        const int k0b = st * BK * 2;
#pragma unroll
        for (int q = 0; q < 4; ++q)
            stage_tile(wh + (size_t)q * OUT_C * OUT_C + (size_t)brow * OUT_C, OUT_C * 2, k0b, q * 8192);
        stage_tile(h0T + (size_t)bcol * OUT_C, OUT_C * 2, k0b, 4 * 8192);
        stage_tile(h1T + (size_t)bcol * OUT_C, OUT_C * 2, k0b, 5 * 8192);
        __syncthreads();
#pragma unroll
        for (int kk = 0; kk < 2; ++kk) {
            const int kbyte = kk * 64 + g4 * 16;
            bf16x8 afr[4][2], b0f[2], b1f[2];
#pragma unroll
            for (int q = 0; q < 4; ++q)
#pragma unroll
                for (int fm = 0; fm < 2; ++fm)
                    afr[q][fm] = frag_at(q * 8192, wm * 32 + fm * 16 + l16, kbyte);
#pragma unroll
            for (int fn = 0; fn < 2; ++fn) {
                b0f[fn] = frag_at(4 * 8192, wn * 32 + fn * 16 + l16, kbyte);
                b1f[fn] = frag_at(5 * 8192, wn * 32 + fn * 16 + l16, kbyte);
            }
#pragma unroll
            for (int q = 0; q < 4; ++q)
#pragma unroll
                for (int fm = 0; fm < 2; ++fm)
#pragma unroll
                    for (int fn = 0; fn < 2; ++fn) {
                        acc[0][q][fm][fn] = __builtin_amdgcn_mfma_f32_16x16x32_bf16(
                            afr[q][fm], b0f[fn], acc[0][q][fm][fn], 0, 0, 0);
                        acc[1][q][fm][fn] = __builtin_amdgcn_mfma_f32_16x16x32_bf16(
                            afr[q][fm], b1f[fn], acc[1][q][fm][fn], 0, 0, 0);
                    }
        }
        __syncthreads();
    }

    // ---------------- epilogue: gates -> c,h -> weighted combine ----------------
    // C/D layout (verified m89): col = lane&15, row = (lane>>4)*4 + reg
    const float w0 = wsum[0], w1 = wsum[1];
#pragma unroll
    for (int fm = 0; fm < 2; ++fm)
#pragma unroll
        for (int fn = 0; fn < 2; ++fn)
#pragma unroll
            for (int r = 0; r < 4; ++r) {
                const int m = brow + wm * 32 + fm * 16 + g4 * 4 + r;
                const int n = bcol + wn * 32 + fn * 16 + l16;
                const size_t idx = (size_t)m * NSAMP + n;
                const float bi = b_i[m], bff = b_f[m], bg = b_g[m], bo = b_o[m];

                float c0v, h0v, c1v, h1v;
                {
                    float i_ = sigmoid_f(acc[0][0][fm][fn][r] + bi);
                    float f_ = sigmoid_f(acc[0][1][fm][fn][r] + bff);
                    float g_ = tanh_f   (acc[0][2][fm][fn][r] + bg);
                    float o_ = sigmoid_f(acc[0][3][fm][fn][r] + bo);
                    float c_ = f_ * cp0[idx] + i_ * g_;
                    c0v = c_;
                    h0v = o_ * tanh_f(c_);
                }
                {
                    float i_ = sigmoid_f(acc[1][0][fm][fn][r] + bi);
                    float f_ = sigmoid_f(acc[1][1][fm][fn][r] + bff);
                    float g_ = tanh_f   (acc[1][2][fm][fn][r] + bg);
                    float o_ = sigmoid_f(acc[1][3][fm][fn][r] + bo);
                    float c_ = f_ * cp1[idx] + i_ * g_;
                    c1v = c_;
                    h1v = o_ * tanh_f(c_);
                }
                out[idx] = w0 * c0v + w1 * c1v;
                out[(size_t)OUT_C * NSAMP + idx] = w0 * h0v + w1 * h1v;
            }
}

extern "C" void kernel_launch(void* const* d_in, const int* in_sizes, int n_in,
                              void* d_out, int out_size, void* d_ws, size_t ws_size,
                              hipStream_t stream) {
    (void)in_sizes; (void)n_in; (void)out_size; (void)ws_size;

    const float* x    = (const float*)d_in[0];
    const float* cp0  = (const float*)d_in[1];
    const float* hp0  = (const float*)d_in[2];
    const float* cp1  = (const float*)d_in[3];
    const float* hp1  = (const float*)d_in[4];
    const float* wxp[4] = {(const float*)d_in[5], (const float*)d_in[6],
                           (const float*)d_in[7], (const float*)d_in[8]};
    const float* whp[4] = {(const float*)d_in[9], (const float*)d_in[10],
                           (const float*)d_in[11], (const float*)d_in[12]};
    const float* b_i  = (const float*)d_in[13];
    const float* b_f  = (const float*)d_in[14];
    const float* b_g  = (const float*)d_in[15];
    const float* b_o  = (const float*)d_in[16];
    const float* wsum = (const float*)d_in[17];
    float* out = (float*)d_out;

    // workspace layout (52 MiB total)
    char* ws = (char*)d_ws;
    unsigned short* xT  = (unsigned short*)(ws);                              //  8 MiB
    unsigned short* h0T = (unsigned short*)(ws + (size_t)8  * 1024 * 1024);   // 16 MiB
    unsigned short* h1T = (unsigned short*)(ws + (size_t)24 * 1024 * 1024);   // 16 MiB
    unsigned short* wxc = (unsigned short*)(ws + (size_t)40 * 1024 * 1024);   //  4 MiB
    unsigned short* whc = (unsigned short*)(ws + (size_t)44 * 1024 * 1024);   //  8 MiB

    dim3 tb(32, 8);
    tcvt_kernel<<<dim3(NSAMP / 32, IN_C  / 32), tb, 0, stream>>>(x,   xT,  IN_C,  NSAMP);
    tcvt_kernel<<<dim3(NSAMP / 32, OUT_C / 32), tb, 0, stream>>>(hp0, h0T, OUT_C, NSAMP);
    tcvt_kernel<<<dim3(NSAMP / 32, OUT_C / 32), tb, 0, stream>>>(hp1, h1T, OUT_C, NSAMP);

    for (int q = 0; q < 4; ++q)
        cvt_kernel<<<(OUT_C * IN_C / 4) / 256, 256, 0, stream>>>(
            wxp[q], wxc + (size_t)q * OUT_C * IN_C, OUT_C * IN_C / 4);
    for (int q = 0; q < 4; ++q)
        cvt_kernel<<<(OUT_C * OUT_C / 4) / 256, 256, 0, stream>>>(
            whp[q], whc + (size_t)q * OUT_C * OUT_C, OUT_C * OUT_C / 4);

    mdlstm_main<<<dim3(NSAMP / BN, OUT_C / BM), 256, 0, stream>>>(
        xT, h0T, h1T, wxc, whc, b_i, b_f, b_g, b_o, cp0, cp1, wsum, out);
}

// Round 4
// 247.570 us; speedup vs baseline: 1.0105x; 1.0105x over previous
//
#include <hip/hip_runtime.h>
#include <cstdint>
#include <cstddef>

#define IN_C  512
#define OUT_C 1024
#define NSAMP 8192

typedef __bf16 bf16x8 __attribute__((ext_vector_type(8)));
typedef float  f32x4  __attribute__((ext_vector_type(4)));

#define VMCNT(N)  asm volatile("s_waitcnt vmcnt(" #N ")" ::: "memory")
#define BARRIER() asm volatile("s_barrier" ::: "memory")

__device__ __forceinline__ unsigned short f2bf(float f) {
    unsigned int u = __float_as_uint(f);
    u += 0x7FFFu + ((u >> 16) & 1u);   // round-to-nearest-even
    return (unsigned short)(u >> 16);
}

__device__ __forceinline__ float sigmoid_f(float x) {
    return 1.0f / (1.0f + __expf(-x));
}
__device__ __forceinline__ float tanh_f(float x) {
    float e = __expf(2.0f * x);
    return 1.0f - 2.0f / (e + 1.0f);
}

// ---- transpose + f32->bf16: in (R x C) row-major -> out (C x R) row-major ----
__global__ void tcvt_kernel(const float* __restrict__ in, unsigned short* __restrict__ out,
                            int R, int C) {
    __shared__ float t[32][33];
    const int tx = threadIdx.x;   // 0..31
    const int ty = threadIdx.y;   // 0..7
    const int c0 = blockIdx.x * 32;
    const int r0 = blockIdx.y * 32;
#pragma unroll
    for (int i = 0; i < 4; ++i)
        t[ty + i * 8][tx] = in[(size_t)(r0 + ty + i * 8) * C + (c0 + tx)];
    __syncthreads();
#pragma unroll
    for (int i = 0; i < 4; ++i)
        out[(size_t)(c0 + ty + i * 8) * R + (r0 + tx)] = f2bf(t[tx][ty + i * 8]);
}

// ---- straight f32->bf16 convert, 4 elems/thread ----
__global__ void cvt_kernel(const float* __restrict__ in, unsigned short* __restrict__ out, int n4) {
    int idx = blockIdx.x * blockDim.x + threadIdx.x;
    if (idx < n4) {
        float4 v = reinterpret_cast<const float4*>(in)[idx];
        ushort4 o;
        o.x = f2bf(v.x); o.y = f2bf(v.y); o.z = f2bf(v.z); o.w = f2bf(v.w);
        reinterpret_cast<ushort4*>(out)[idx] = o;
    }
}

// MFMA cluster for one phase: gates G0,G1 x ND dirs x fm x fn
template<int G0, int G1, int ND>
__device__ __forceinline__ void mfma_phase(f32x4 (&acc)[2][4][2][2],
                                           const bf16x8 (&aF0)[2],
                                           const bf16x8 (&aF1)[2],
                                           const bf16x8 (&bF)[2][2]) {
    __builtin_amdgcn_s_setprio(1);
#pragma unroll
    for (int d = 0; d < ND; ++d)
#pragma unroll
        for (int fm = 0; fm < 2; ++fm)
#pragma unroll
            for (int fn = 0; fn < 2; ++fn) {
                acc[d][G0][fm][fn] = __builtin_amdgcn_mfma_f32_16x16x32_bf16(
                    aF0[fm], bF[d][fn], acc[d][G0][fm][fn], 0, 0, 0);
                acc[d][G1][fm][fn] = __builtin_amdgcn_mfma_f32_16x16x32_bf16(
                    aF1[fm], bF[d][fn], acc[d][G1][fm][fn], 0, 0, 0);
            }
    __builtin_amdgcn_s_setprio(0);
}

// ---- fused MDLSTM: BM=64 x BN=128 tile, 8 waves, 4-phase K-steps,
// ---- double-buffered LDS with counted-vmcnt half-tile pipeline ----
__global__ __launch_bounds__(512, 2) void mdlstm_main(
    const unsigned short* __restrict__ xT,    // [NSAMP][IN_C]  bf16
    const unsigned short* __restrict__ h0T,   // [NSAMP][OUT_C] bf16
    const unsigned short* __restrict__ h1T,   // [NSAMP][OUT_C] bf16
    const unsigned short* __restrict__ wx,    // [4][OUT_C][IN_C]  bf16 (i,f,g,o)
    const unsigned short* __restrict__ wh,    // [4][OUT_C][OUT_C] bf16
    const float* __restrict__ b_i, const float* __restrict__ b_f,
    const float* __restrict__ b_g, const float* __restrict__ b_o,
    const float* __restrict__ cp0, const float* __restrict__ cp1,
    const float* __restrict__ wsum,
    float* __restrict__ out)
{
    // 2 buffers x (2 kk-halves x (A:4x4KB + B0:8KB + B1:8KB)) = 2 x 64KB
    __shared__ __align__(16) unsigned char smem[131072];

    const int tid  = threadIdx.x;
    const int lane = tid & 63;
    const int wid  = tid >> 6;      // 0..7
    const int wm   = wid >> 2;      // 0..1 wave row (32 out-rows each)
    const int wn   = wid & 3;       // 0..3 wave col (32 out-cols each)
    const int g4   = lane >> 4;     // 0..3
    const int l16  = lane & 15;

    const int brow = blockIdx.y * 64;
    const int bcol = blockIdx.x * 128;

    const int s_off16 = tid * 16;   // this thread's 16B staging slot

    f32x4 acc[2][4][2][2];
#pragma unroll
    for (int d = 0; d < 2; ++d)
#pragma unroll
        for (int q = 0; q < 4; ++q)
#pragma unroll
            for (int a = 0; a < 2; ++a)
#pragma unroll
                for (int b = 0; b < 2; ++b)
                    acc[d][q][a][b] = (f32x4){0.f, 0.f, 0.f, 0.f};

    // swizzle within a 64B (32-elem) k-half row: slot = (row>>1)&3
    // A kk-half: 4 gates x 64 rows x 32k = 16KB -> 2 issues/thread
    auto stage_A_half = [&](int buf, int h, const unsigned short* w, int pitchE, int k0) {
#pragma unroll
        for (int i = 0; i < 2; ++i) {
            const int u   = i * 8192 + s_off16;
            const int q   = u >> 12;            // gate
            const int v   = u & 4095;
            const int row = v >> 6;             // 0..63
            const int kb  = v & 63;
            const char* src = (const char*)w
                + ((size_t)q * OUT_C * pitchE + (size_t)(brow + row) * pitchE + k0 + h * 32) * 2
                + (kb ^ ((((row >> 1) & 3)) << 4));
            __builtin_amdgcn_global_load_lds((const unsigned int*)src,
                (unsigned int*)(smem + buf * 65536 + h * 32768 + i * 8192 + s_off16), 16, 0, 0);
        }
    };
    // B kk-half (one dir): 128 rows x 32k = 8KB -> 1 issue/thread
    auto stage_B_half = [&](int buf, int h, int d, const unsigned short* hT, int pitchE, int k0) {
        const int row = s_off16 >> 6;           // 0..127
        const int kb  = s_off16 & 63;
        const char* src = (const char*)hT
            + ((size_t)(bcol + row) * pitchE + k0 + h * 32) * 2
            + (kb ^ ((((row >> 1) & 3)) << 4));
        __builtin_amdgcn_global_load_lds((const unsigned int*)src,
            (unsigned int*)(smem + buf * 65536 + h * 32768 + 16384 + d * 8192 + s_off16), 16, 0, 0);
    };

    auto fragA = [&](int buf, int h, int q, int fm) -> bf16x8 {
        const int row = wm * 32 + fm * 16 + l16;
        const int off = buf * 65536 + h * 32768 + q * 4096 + row * 64
                        + ((g4 * 16) ^ ((((row >> 1) & 3)) << 4));
        return *reinterpret_cast<const bf16x8*>(smem + off);
    };
    auto fragB = [&](int buf, int h, int d, int fn) -> bf16x8 {
        const int row = wn * 32 + fn * 16 + l16;
        const int off = buf * 65536 + h * 32768 + 16384 + d * 8192 + row * 64
                        + ((g4 * 16) ^ ((((row >> 1) & 3)) << 4));
        return *reinterpret_cast<const bf16x8*>(smem + off);
    };

    bf16x8 aF0[2], aF1[2];    // current phase's A frags (gate pair)
    bf16x8 bF[2][2];          // [dir][fn], live across a kk-half (2 phases)

    // ---------------- prologue: stage X tile 0 (kk0 first, then kk1) ----------------
    stage_A_half(0, 0, wx, IN_C, 0);
    stage_B_half(0, 0, 0, xT, IN_C, 0);
    stage_A_half(0, 1, wx, IN_C, 0);
    stage_B_half(0, 1, 0, xT, IN_C, 0);
    VMCNT(3);      // kk0(X0) done; kk1(X0)'s 3 loads still in flight
    BARRIER();

    // ---------------- X phase: K=512, 8 K-steps ----------------
    for (int st = 0; st < 8; ++st) {
        const int cur = st & 1, nxt = cur ^ 1;
        const bool last = (st == 7);
        const int k0n = last ? 0 : (st + 1) * 64;

        // ---- p0: kk0, gates 0,1 ----
#pragma unroll
        for (int fn = 0; fn < 2; ++fn) bF[0][fn] = fragB(cur, 0, 0, fn);
#pragma unroll
        for (int fm = 0; fm < 2; ++fm) { aF0[fm] = fragA(cur, 0, 0, fm); aF1[fm] = fragA(cur, 0, 1, fm); }
        if (!last) stage_A_half(nxt, 0, wx, IN_C, k0n);
        else       stage_A_half(nxt, 0, wh, OUT_C, 0);
        BARRIER();
        mfma_phase<0, 1, 1>(acc, aF0, aF1, bF);
        BARRIER();

        // ---- p1: kk0, gates 2,3 ----
#pragma unroll
        for (int fm = 0; fm < 2; ++fm) { aF0[fm] = fragA(cur, 0, 2, fm); aF1[fm] = fragA(cur, 0, 3, fm); }
        if (!last) { stage_B_half(nxt, 0, 0, xT, IN_C, k0n); }
        else       { stage_B_half(nxt, 0, 0, h0T, OUT_C, 0); stage_B_half(nxt, 0, 1, h1T, OUT_C, 0); }
        BARRIER();
        mfma_phase<2, 3, 1>(acc, aF0, aF1, bF);
        if (!last) { VMCNT(3); } else { VMCNT(4); }   // kk1(cur) complete
        BARRIER();

        // ---- p2: kk1, gates 0,1 ----
#pragma unroll
        for (int fn = 0; fn < 2; ++fn) bF[0][fn] = fragB(cur, 1, 0, fn);
#pragma unroll
        for (int fm = 0; fm < 2; ++fm) { aF0[fm] = fragA(cur, 1, 0, fm); aF1[fm] = fragA(cur, 1, 1, fm); }
        if (!last) stage_A_half(nxt, 1, wx, IN_C, k0n);
        else       stage_A_half(nxt, 1, wh, OUT_C, 0);
        BARRIER();
        mfma_phase<0, 1, 1>(acc, aF0, aF1, bF);
        BARRIER();

        // ---- p3: kk1, gates 2,3 ----
#pragma unroll
        for (int fm = 0; fm < 2; ++fm) { aF0[fm] = fragA(cur, 1, 2, fm); aF1[fm] = fragA(cur, 1, 3, fm); }
        if (!last) { stage_B_half(nxt, 1, 0, xT, IN_C, k0n); }
        else       { stage_B_half(nxt, 1, 0, h0T, OUT_C, 0); stage_B_half(nxt, 1, 1, h1T, OUT_C, 0); }
        BARRIER();
        mfma_phase<2, 3, 1>(acc, aF0, aF1, bF);
        if (!last) { VMCNT(3); } else { VMCNT(4); }   // kk0(next) complete
        BARRIER();
    }

    // x-projection shared by both directions
#pragma unroll
    for (int q = 0; q < 4; ++q)
#pragma unroll
        for (int a = 0; a < 2; ++a)
#pragma unroll
            for (int b = 0; b < 2; ++b)
                acc[1][q][a][b] = acc[0][q][a][b];

    // ---------------- H phase: K=1024, 16 K-steps, 2 dirs ----------------
    for (int st = 0; st < 16; ++st) {
        const int cur = st & 1, nxt = cur ^ 1;
        const bool last = (st == 15);
        const int k0n = last ? 0 : (st + 1) * 64;

        // ---- p0: kk0, gates 0,1 ----
#pragma unroll
        for (int d = 0; d < 2; ++d)
#pragma unroll
            for (int fn = 0; fn < 2; ++fn) bF[d][fn] = fragB(cur, 0, d, fn);
#pragma unroll
        for (int fm = 0; fm < 2; ++fm) { aF0[fm] = fragA(cur, 0, 0, fm); aF1[fm] = fragA(cur, 0, 1, fm); }
        if (!last) stage_A_half(nxt, 0, wh, OUT_C, k0n);
        BARRIER();
        mfma_phase<0, 1, 2>(acc, aF0, aF1, bF);
        BARRIER();

        // ---- p1: kk0, gates 2,3 ----
#pragma unroll
        for (int fm = 0; fm < 2; ++fm) { aF0[fm] = fragA(cur, 0, 2, fm); aF1[fm] = fragA(cur, 0, 3, fm); }
        if (!last) { stage_B_half(nxt, 0, 0, h0T, OUT_C, k0n); stage_B_half(nxt, 0, 1, h1T, OUT_C, k0n); }
        BARRIER();
        mfma_phase<2, 3, 2>(acc, aF0, aF1, bF);
        if (!last) { VMCNT(4); } else { VMCNT(0); }   // kk1(cur) complete
        BARRIER();

        // ---- p2: kk1, gates 0,1 ----
#pragma unroll
        for (int d = 0; d < 2; ++d)
#pragma unroll
            for (int fn = 0; fn < 2; ++fn) bF[d][fn] = fragB(cur, 1, d, fn);
#pragma unroll
        for (int fm = 0; fm < 2; ++fm) { aF0[fm] = fragA(cur, 1, 0, fm); aF1[fm] = fragA(cur, 1, 1, fm); }
        if (!last) stage_A_half(nxt, 1, wh, OUT_C, k0n);
        BARRIER();
        mfma_phase<0, 1, 2>(acc, aF0, aF1, bF);
        BARRIER();

        // ---- p3: kk1, gates 2,3 ----
#pragma unroll
        for (int fm = 0; fm < 2; ++fm) { aF0[fm] = fragA(cur, 1, 2, fm); aF1[fm] = fragA(cur, 1, 3, fm); }
        if (!last) { stage_B_half(nxt, 1, 0, h0T, OUT_C, k0n); stage_B_half(nxt, 1, 1, h1T, OUT_C, k0n); }
        BARRIER();
        mfma_phase<2, 3, 2>(acc, aF0, aF1, bF);
        if (!last) { VMCNT(4); BARRIER(); }           // kk0(next) complete
    }

    // ---------------- epilogue ----------------
    const float w0 = wsum[0], w1 = wsum[1];
#pragma unroll
    for (int fm = 0; fm < 2; ++fm)
#pragma unroll
        for (int fn = 0; fn < 2; ++fn)
#pragma unroll
            for (int r = 0; r < 4; ++r) {
                const int m = brow + wm * 32 + fm * 16 + g4 * 4 + r;
                const int n = bcol + wn * 32 + fn * 16 + l16;
                const size_t idx = (size_t)m * NSAMP + n;
                const float bi = b_i[m], bff = b_f[m], bg = b_g[m], bo = b_o[m];

                float c0v, h0v, c1v, h1v;
                {
                    float i_ = sigmoid_f(acc[0][0][fm][fn][r] + bi);
                    float f_ = sigmoid_f(acc[0][1][fm][fn][r] + bff);
                    float g_ = tanh_f   (acc[0][2][fm][fn][r] + bg);
                    float o_ = sigmoid_f(acc[0][3][fm][fn][r] + bo);
                    float c_ = f_ * cp0[idx] + i_ * g_;
                    c0v = c_;
                    h0v = o_ * tanh_f(c_);
                }
                {
                    float i_ = sigmoid_f(acc[1][0][fm][fn][r] + bi);
                    float f_ = sigmoid_f(acc[1][1][fm][fn][r] + bff);
                    float g_ = tanh_f   (acc[1][2][fm][fn][r] + bg);
                    float o_ = sigmoid_f(acc[1][3][fm][fn][r] + bo);
                    float c_ = f_ * cp1[idx] + i_ * g_;
                    c1v = c_;
                    h1v = o_ * tanh_f(c_);
                }
                out[idx] = w0 * c0v + w1 * c1v;
                out[(size_t)OUT_C * NSAMP + idx] = w0 * h0v + w1 * h1v;
            }
}

extern "C" void kernel_launch(void* const* d_in, const int* in_sizes, int n_in,
                              void* d_out, int out_size, void* d_ws, size_t ws_size,
                              hipStream_t stream) {
    (void)in_sizes; (void)n_in; (void)out_size; (void)ws_size;

    const float* x    = (const float*)d_in[0];
    const float* cp0  = (const float*)d_in[1];
    const float* hp0  = (const float*)d_in[2];
    const float* cp1  = (const float*)d_in[3];
    const float* hp1  = (const float*)d_in[4];
    const float* wxp[4] = {(const float*)d_in[5], (const float*)d_in[6],
                           (const float*)d_in[7], (const float*)d_in[8]};
    const float* whp[4] = {(const float*)d_in[9], (const float*)d_in[10],
                           (const float*)d_in[11], (const float*)d_in[12]};
    const float* b_i  = (const float*)d_in[13];
    const float* b_f  = (const float*)d_in[14];
    const float* b_g  = (const float*)d_in[15];
    const float* b_o  = (const float*)d_in[16];
    const float* wsum = (const float*)d_in[17];
    float* out = (float*)d_out;

    // workspace layout (52 MiB total)
    char* ws = (char*)d_ws;
    unsigned short* xT  = (unsigned short*)(ws);                              //  8 MiB
    unsigned short* h0T = (unsigned short*)(ws + (size_t)8  * 1024 * 1024);   // 16 MiB
    unsigned short* h1T = (unsigned short*)(ws + (size_t)24 * 1024 * 1024);   // 16 MiB
    unsigned short* wxc = (unsigned short*)(ws + (size_t)40 * 1024 * 1024);   //  4 MiB
    unsigned short* whc = (unsigned short*)(ws + (size_t)44 * 1024 * 1024);   //  8 MiB

    dim3 tb(32, 8);
    tcvt_kernel<<<dim3(NSAMP / 32, IN_C  / 32), tb, 0, stream>>>(x,   xT,  IN_C,  NSAMP);
    tcvt_kernel<<<dim3(NSAMP / 32, OUT_C / 32), tb, 0, stream>>>(hp0, h0T, OUT_C, NSAMP);
    tcvt_kernel<<<dim3(NSAMP / 32, OUT_C / 32), tb, 0, stream>>>(hp1, h1T, OUT_C, NSAMP);

    for (int q = 0; q < 4; ++q)
        cvt_kernel<<<(OUT_C * IN_C / 4) / 256, 256, 0, stream>>>(
            wxp[q], wxc + (size_t)q * OUT_C * IN_C, OUT_C * IN_C / 4);
    for (int q = 0; q < 4; ++q)
        cvt_kernel<<<(OUT_C * OUT_C / 4) / 256, 256, 0, stream>>>(
            whp[q], whc + (size_t)q * OUT_C * OUT_C, OUT_C * OUT_C / 4);

    mdlstm_main<<<dim3(NSAMP / 128, OUT_C / 64), 512, 0, stream>>>(
        xT, h0T, h1T, wxc, whc, b_i, b_f, b_g, b_o, cp0, cp1, wsum, out);
}